// Round 16
// baseline (3039.345 us; speedup 1.0000x reference)
//
#include <hip/hip_runtime.h>
#include <hip/hip_bf16.h>
#include <math.h>

#define BB 64
#define LL 64
#define EE 512
#define HH 512
#define G4 2048
#define VT 32000
#define RT 4096  // LL*BB

typedef unsigned short u16;
typedef unsigned int u32;
typedef unsigned char u8;
typedef __attribute__((ext_vector_type(2))) unsigned int u32x2;
typedef __attribute__((ext_vector_type(8))) unsigned short ushort8;
typedef __attribute__((ext_vector_type(8))) short bf16x8;
typedef __attribute__((ext_vector_type(4))) float f32x4;

// ---------------- static device scratch ----------------
__device__ u16   gW2T[(size_t)VT * 1024];   // h2o_W^T (VT x 1024) bf16
__device__ u16   gEncWxT[G4 * EE];
__device__ u16   gEncWhT[G4 * HH];
__device__ u16   gAttWhT[HH * HH];
__device__ u16   gDecWxTe[G4 * EE];
__device__ u16   gDecWxTc[G4 * HH];
__device__ u16   gDecWhT[G4 * HH];
__device__ u8    gWs8[HH * HH];             // att_Ws fp8 e4m3, [k][c] layout
__device__ u16   gSrcEmb[RT * EE];
__device__ u16   gTgtEmb[RT * EE];
__device__ float gXWxE[(size_t)RT * G4];    // src_emb @ enc_Wx + enc_b
__device__ float gXWxD[(size_t)RT * G4];    // tgt_emb @ dec_Wx[:512] + dec_b
__device__ u16   gEncHb[(size_t)RT * HH];   // enc h bf16, [t*64+b][h]
__device__ u16   gEncHb2[(size_t)RT * HH];  // enc h bf16, [b*64+t][h]
__device__ u16   gEncTb[(size_t)RT * HH];   // enc_hiddens @ att_Wh, bf16 [b*64+s][h]
__device__ u16   gHcat[(size_t)RT * 1024];  // [h | ctx] bf16, row rr=t*64+b
__device__ float gC[BB * HH];               // LSTM cell state
__device__ float gAv[HH];
__device__ unsigned gFlagE[64];             // encoder: per-block h-ready generation
__device__ unsigned gFlagB[64];             // decoder: ctx ready, row b
__device__ unsigned gFlagC[64];             // decoder: h ready, [chain*32 + colslice]
__device__ unsigned gStep;                  // chain A aggregated progress
__device__ unsigned gStep2;                 // chain B aggregated progress

__device__ __forceinline__ u16 f2b(float f) {
    union { float f; unsigned u; } v{f};
    unsigned r = v.u + 0x7fffu + ((v.u >> 16) & 1u);
    return (u16)(r >> 16);
}
__device__ __forceinline__ float b2f(u16 x) {
    union { unsigned u; float f; } v; v.u = ((unsigned)x) << 16; return v.f;
}
__device__ __forceinline__ float sigm(float x) { return 1.f / (1.f + __expf(-x)); }
__device__ __forceinline__ float ftanh(float x) {
    x = fminf(15.f, fmaxf(-15.f, x));
    float e = __expf(2.f * x);
    return (e - 1.f) / (e + 1.f);
}

// ---- fp8 e4m3 encode (preamble only) / decode (hot loop) ----
__device__ unsigned char encf8(float f) {
    union { float f; unsigned u; } v{f};
    unsigned s = (v.u >> 31) << 7;
    float af = fabsf(f);
    if (af < 0.0009765625f) return (unsigned char)s;
    if (af >= 448.f) return (unsigned char)(s | 0x7E);
    if (af < 0.015625f) {
        int q = (int)rintf(af * 512.f);
        if (q >= 8) return (unsigned char)(s | 0x08);
        return (unsigned char)(s | q);
    }
    int e; float m = frexpf(af, &e);
    int E = e - 1 + 7;
    int q = (int)rintf((m * 2.f - 1.f) * 8.f);
    if (q == 8) { E++; q = 0; }
    if (E >= 15) return (unsigned char)(s | 0x7E);
    return (unsigned char)(s | (E << 3) | q);
}
__device__ __forceinline__ float decf8s(unsigned v) {
    unsigned s = v >> 7, e = (v >> 3) & 15, m = v & 7;
    float mag = e ? ldexpf((float)(8 + m), (int)e - 10) : ldexpf((float)m, -9);
    return s ? -mag : mag;
}
#if __has_builtin(__builtin_amdgcn_cvt_f32_fp8)
#define DEC8(w, sel) __builtin_amdgcn_cvt_f32_fp8((int)(w), sel)
#else
#define DEC8(w, sel) decf8s(((w) >> (8 * (sel))) & 0xFFu)
#endif

// ---- L2-bypass (MALL-coherent) memory helpers ----
__device__ __forceinline__ void ld16(const void* addr, bf16x8* a) {
    asm volatile(
        "global_load_dwordx4 %0, %16, off sc0 sc1\n\t"
        "global_load_dwordx4 %1, %16, off offset:64 sc0 sc1\n\t"
        "global_load_dwordx4 %2, %16, off offset:128 sc0 sc1\n\t"
        "global_load_dwordx4 %3, %16, off offset:192 sc0 sc1\n\t"
        "global_load_dwordx4 %4, %16, off offset:256 sc0 sc1\n\t"
        "global_load_dwordx4 %5, %16, off offset:320 sc0 sc1\n\t"
        "global_load_dwordx4 %6, %16, off offset:384 sc0 sc1\n\t"
        "global_load_dwordx4 %7, %16, off offset:448 sc0 sc1\n\t"
        "global_load_dwordx4 %8, %16, off offset:512 sc0 sc1\n\t"
        "global_load_dwordx4 %9, %16, off offset:576 sc0 sc1\n\t"
        "global_load_dwordx4 %10, %16, off offset:640 sc0 sc1\n\t"
        "global_load_dwordx4 %11, %16, off offset:704 sc0 sc1\n\t"
        "global_load_dwordx4 %12, %16, off offset:768 sc0 sc1\n\t"
        "global_load_dwordx4 %13, %16, off offset:832 sc0 sc1\n\t"
        "global_load_dwordx4 %14, %16, off offset:896 sc0 sc1\n\t"
        "global_load_dwordx4 %15, %16, off offset:960 sc0 sc1\n\t"
        "s_waitcnt vmcnt(0)"
        : "=&v"(a[0]), "=&v"(a[1]), "=&v"(a[2]), "=&v"(a[3]),
          "=&v"(a[4]), "=&v"(a[5]), "=&v"(a[6]), "=&v"(a[7]),
          "=&v"(a[8]), "=&v"(a[9]), "=&v"(a[10]), "=&v"(a[11]),
          "=&v"(a[12]), "=&v"(a[13]), "=&v"(a[14]), "=&v"(a[15])
        : "v"(addr) : "memory");
}
__device__ __forceinline__ u32 ld1(const void* addr) {
    u32 r;
    asm volatile("global_load_dword %0, %1, off sc0 sc1\n\ts_waitcnt vmcnt(0)"
                 : "=&v"(r) : "v"(addr) : "memory");
    return r;
}
__device__ __forceinline__ void st8b(void* p, u32x2 v) {
    asm volatile("global_store_dwordx2 %0, %1, off sc0 sc1" :: "v"(p), "v"(v) : "memory");
}
__device__ __forceinline__ void st32b(u32* p, u32 v) {
    asm volatile("global_store_dword %0, %1, off sc0 sc1" :: "v"(p), "v"(v) : "memory");
}

__device__ __forceinline__ void setflag(unsigned* f, unsigned v) {
    asm volatile("s_waitcnt vmcnt(0)" ::: "memory");
    __syncthreads();
    if (threadIdx.x == 0) st32b((u32*)f, v);
}
__device__ __forceinline__ void waitflags(unsigned* flags, int n, unsigned target) {
    if (threadIdx.x < 64) {
        const unsigned* p = flags + (threadIdx.x & (n - 1));
        for (;;) {
            u32 v = ld1(p);
            if (__all(v >= target)) break;
            __builtin_amdgcn_s_sleep(1);
        }
    }
    __syncthreads();
}

__device__ __forceinline__ void g2l16(const u16* g, u16* l) {
    __builtin_amdgcn_global_load_lds(
        (const __attribute__((address_space(1))) unsigned int*)g,
        (__attribute__((address_space(3))) unsigned int*)l, 16, 0, 0);
}
__device__ __forceinline__ void g2l16nt(const u16* g, u16* l) {
    __builtin_amdgcn_global_load_lds(
        (const __attribute__((address_space(1))) unsigned int*)g,
        (__attribute__((address_space(3))) unsigned int*)l, 16, 0, 2);
}

// ---------------- transpose fp32 (R x C) -> bf16 (C x R), small weights ----------------
__device__ inline u16* bf16sel(int s) {
    switch (s) {
        case 1: return gEncWxT; case 2: return gEncWhT;
        case 3: return gAttWhT; case 4: return gDecWxTe; case 5: return gDecWxTc;
        default: return gDecWhT;
    }
}

__global__ __launch_bounds__(256) void k_transpose(const float* __restrict__ in, int R, int C, int sel) {
    __shared__ float tile[32][33];
    int tx = threadIdx.x & 31, ty0 = threadIdx.x >> 5;
    int c0 = blockIdx.x * 32, r0 = blockIdx.y * 32;
#pragma unroll
    for (int k = 0; k < 4; k++) {
        int ty = ty0 + k * 8;
        tile[ty][tx] = in[(size_t)(r0 + ty) * C + c0 + tx];
    }
    __syncthreads();
    u16* out = bf16sel(sel);
#pragma unroll
    for (int k = 0; k < 4; k++) {
        int ty = ty0 + k * 8;
        out[(size_t)(c0 + ty) * R + r0 + tx] = f2b(tile[tx][ty]);
    }
}

__global__ __launch_bounds__(256) void k_tofp8(const float* __restrict__ in) {
    int i = blockIdx.x * 256 + threadIdx.x;
    gWs8[i] = encf8(in[i]);
}

__global__ __launch_bounds__(256) void k_gather(const int* __restrict__ tok, const float* __restrict__ tab, int sel) {
    int r = blockIdx.x;
    int b = r & 63, t = r >> 6;
    int token = tok[b * LL + t];
    u16* dst = (sel == 0) ? gSrcEmb : gTgtEmb;
    const float* srow = tab + (size_t)token * EE;
    for (int e = threadIdx.x; e < EE; e += 256)
        dst[(size_t)r * EE + e] = f2b(srow[e]);
}

__global__ __launch_bounds__(256) void k_zero() {
    int i = blockIdx.x * 256 + threadIdx.x;  // 128 blocks
    gC[i] = 0.f;
    if (i < 64) st32b((u32*)(gFlagE + i), 0u);
}

__global__ __launch_bounds__(256) void k_rst(const float* __restrict__ av) {
    int t = threadIdx.x;
    gAv[t] = av[t];
    gAv[t + 256] = av[t + 256];
    if (t < 64) {
        st32b((u32*)(gFlagB + t), 0u);
        st32b((u32*)(gFlagC + t), 0u);
    }
    if (t == 0) { st32b((u32*)&gStep, 0u); st32b((u32*)&gStep2, 0u); }
}

// ---------------- generic bf16 MFMA GEMM (preamble): epi2 fp32+bias, epi4 bf16 b-major ----------------
__global__ __launch_bounds__(256) void k_gemm(int selA, int lda, int selB, int ldb,
                                              int M, int N, int K, int epi,
                                              const float* __restrict__ bias, int selOut) {
    __shared__ u16 sA[128 * 72];
    __shared__ u16 sB[128 * 72];
    const u16* Ag = (selA == 0) ? gSrcEmb : gEncHb;
    const u16* Bg = (selB == 0) ? gEncWxT : gAttWhT;
    float* Cg = gXWxE;

    int tid = threadIdx.x, l = tid & 63, wid = tid >> 6, wr = wid >> 1, wc = wid & 1;
    int ar = l & 15, ak = (l >> 4) * 8;
    int rowM = blockIdx.y * 128, colN = blockIdx.x * 128;
    f32x4 acc[4][4];
#pragma unroll
    for (int m = 0; m < 4; m++)
#pragma unroll
        for (int n = 0; n < 4; n++) acc[m][n] = (f32x4){0.f, 0.f, 0.f, 0.f};

    for (int k0 = 0; k0 < K; k0 += 64) {
#pragma unroll
        for (int it = 0; it < 4; it++) {
            int idx = it * 256 + tid;
            int row = idx >> 3, cc = idx & 7;
            *(ushort8*)(sA + row * 72 + cc * 8) =
                *(const ushort8*)(Ag + (size_t)(rowM + row) * lda + k0 + cc * 8);
            *(ushort8*)(sB + row * 72 + cc * 8) =
                *(const ushort8*)(Bg + (size_t)(colN + row) * ldb + k0 + cc * 8);
        }
        __syncthreads();
#pragma unroll
        for (int ks = 0; ks < 2; ks++) {
            bf16x8 a[4], b[4];
#pragma unroll
            for (int m = 0; m < 4; m++) a[m] = *(const bf16x8*)(sA + (wr * 64 + m * 16 + ar) * 72 + ks * 32 + ak);
#pragma unroll
            for (int n = 0; n < 4; n++) b[n] = *(const bf16x8*)(sB + (wc * 64 + n * 16 + ar) * 72 + ks * 32 + ak);
#pragma unroll
            for (int m = 0; m < 4; m++)
#pragma unroll
                for (int n = 0; n < 4; n++)
                    acc[m][n] = __builtin_amdgcn_mfma_f32_16x16x32_bf16(a[m], b[n], acc[m][n], 0, 0, 0);
        }
        __syncthreads();
    }
    int rb = (l >> 4) * 4;
#pragma unroll
    for (int m = 0; m < 4; m++)
#pragma unroll
        for (int n = 0; n < 4; n++)
#pragma unroll
            for (int ri = 0; ri < 4; ri++) {
                int row = rowM + wr * 64 + m * 16 + rb + ri;
                int col = colN + wc * 64 + n * 16 + ar;
                float v = acc[m][n][ri];
                if (epi == 2) Cg[(size_t)row * N + col] = v + bias[col];
                else gEncTb[(size_t)((row & 63) * 64 + (row >> 6)) * N + col] = f2b(v);
            }
}

// ---- encoder + co-launched helpers: cooperative, 256 blocks (R15-proven) ----
__global__ __launch_bounds__(256) void k_encoder(const float* __restrict__ dec_b,
                                                 const float* __restrict__ h2o_W) {
    __shared__ char smem[67584];
    int tid = threadIdx.x, l = tid & 63, wid = tid >> 6;
    int bx = blockIdx.x;
    int ar = l & 15, ak = (l >> 4) * 8, rb = (l >> 4) * 4;
    if (bx < 32) {
        u16* sW = (u16*)smem;
        u16* s_hout = (u16*)(smem + 65536);
        int j = bx;
#pragma unroll
        for (int it = 0; it < 16; it++) {
            int idx = it * 256 + tid;
            int lr = idx >> 6, kc = idx & 63;
            int gcol = (lr >> 4) * 512 + j * 16 + (lr & 15);
            int off = (lr * 1024 + kc * 16) ^ ((lr & 7) << 4);
            *(ushort8*)((char*)sW + off) = *(const ushort8*)(gEncWhT + (size_t)gcol * 512 + kc * 8);
        }
        __syncthreads();
        int arow = wid * 16 + ar, aoff = (l >> 4) * 16;
        int hcol = j * 16 + ar;
        for (int t = 0; t < LL; t++) {
            float xwv[4][4];
#pragma unroll
            for (int ri = 0; ri < 4; ri++) {
                const float* xw = gXWxE + (size_t)(t * BB + wid * 16 + rb + ri) * G4;
#pragma unroll
                for (int g = 0; g < 4; g++) xwv[ri][g] = xw[g * 512 + hcol];
            }
            f32x4 acc[4];
#pragma unroll
            for (int g = 0; g < 4; g++) acc[g] = (f32x4){0.f, 0.f, 0.f, 0.f};
            if (t > 0) {
                waitflags(gFlagE, 32, (unsigned)t);
                bf16x8 af[16];
                ld16((const char*)gEncHb + (size_t)((t - 1) * BB + arow) * 1024 + aoff, af);
#pragma unroll
                for (int kk = 0; kk < 16; kk++) {
                    int k = kk * 32 + ak;
#pragma unroll
                    for (int g = 0; g < 4; g++) {
                        int lr = g * 16 + ar;
                        bf16x8 b = *(const bf16x8*)((char*)sW + ((lr * 1024 + k * 2) ^ ((lr & 7) << 4)));
                        acc[g] = __builtin_amdgcn_mfma_f32_16x16x32_bf16(af[kk], b, acc[g], 0, 0, 0);
                    }
                }
            }
#pragma unroll
            for (int ri = 0; ri < 4; ri++) {
                int row = wid * 16 + rb + ri;
                float zi = acc[0][ri] + xwv[ri][0];
                float zf = acc[1][ri] + xwv[ri][1];
                float zg = acc[2][ri] + xwv[ri][2];
                float zo = acc[3][ri] + xwv[ri][3];
                float co = gC[row * HH + hcol];
                float cn = sigm(zf) * co + sigm(zi) * ftanh(zg);
                float hn = sigm(zo) * ftanh(cn);
                gC[row * HH + hcol] = cn;
                s_hout[row * 16 + ar] = f2b(hn);
            }
            __syncthreads();
            {
                int row = tid >> 2, seg = tid & 3;
                u32x2 v = *(const u32x2*)(s_hout + row * 16 + seg * 4);
                st8b(gEncHb + (size_t)(t * BB + row) * HH + j * 16 + seg * 4, v);
                *(u32x2*)(gEncHb2 + (size_t)(row * LL + t) * HH + j * 16 + seg * 4) = v;
            }
            setflag(gFlagE + j, (unsigned)(t + 1));
        }
    } else if (bx < 96) {
        u16* sA = (u16*)smem;
        u16* sB = (u16*)(smem + 18432);
        int wr = wid >> 1, wc = wid & 1;
        for (int it8 = 0; it8 < 8; it8++) {
            int ti = (bx - 32) * 8 + it8;
            int bxx = ti & 15, byy = ti >> 4;
            int rowM = byy * 128, colN = bxx * 128;
            f32x4 acc[4][4];
#pragma unroll
            for (int m = 0; m < 4; m++)
#pragma unroll
                for (int n = 0; n < 4; n++) acc[m][n] = (f32x4){0.f, 0.f, 0.f, 0.f};
            for (int k0 = 0; k0 < 512; k0 += 64) {
#pragma unroll
                for (int it = 0; it < 4; it++) {
                    int idx = it * 256 + tid;
                    int row = idx >> 3, cc = idx & 7;
                    *(ushort8*)(sA + row * 72 + cc * 8) =
                        *(const ushort8*)(gTgtEmb + (size_t)(rowM + row) * 512 + k0 + cc * 8);
                    *(ushort8*)(sB + row * 72 + cc * 8) =
                        *(const ushort8*)(gDecWxTe + (size_t)(colN + row) * 512 + k0 + cc * 8);
                }
                __syncthreads();
#pragma unroll
                for (int ks = 0; ks < 2; ks++) {
                    bf16x8 a[4], b[4];
#pragma unroll
                    for (int m = 0; m < 4; m++) a[m] = *(const bf16x8*)(sA + (wr * 64 + m * 16 + ar) * 72 + ks * 32 + ak);
#pragma unroll
                    for (int n = 0; n < 4; n++) b[n] = *(const bf16x8*)(sB + (wc * 64 + n * 16 + ar) * 72 + ks * 32 + ak);
#pragma unroll
                    for (int m = 0; m < 4; m++)
#pragma unroll
                        for (int n = 0; n < 4; n++)
                            acc[m][n] = __builtin_amdgcn_mfma_f32_16x16x32_bf16(a[m], b[n], acc[m][n], 0, 0, 0);
                }
                __syncthreads();
            }
#pragma unroll
            for (int m = 0; m < 4; m++)
#pragma unroll
                for (int n = 0; n < 4; n++)
#pragma unroll
                    for (int ri = 0; ri < 4; ri++) {
                        int row = rowM + wr * 64 + m * 16 + rb + ri;
                        int col = colN + wc * 64 + n * 16 + ar;
                        gXWxD[(size_t)row * G4 + col] = acc[m][n][ri] + dec_b[col];
                    }
        }
    } else {
        float (*tile)[33] = (float(*)[33])smem;
        int tx = tid & 31, ty0 = tid >> 5;
        for (int k = 0; k < 200; k++) {
            int ti = (bx - 96) * 200 + k;
            int ct = ti % 1000, rt = ti / 1000;
            int c0 = ct * 32, r0 = rt * 32;
            __syncthreads();
#pragma unroll
            for (int kk = 0; kk < 4; kk++) {
                int ty = ty0 + kk * 8;
                tile[ty][tx] = h2o_W[(size_t)(r0 + ty) * VT + c0 + tx];
            }
            __syncthreads();
#pragma unroll
            for (int kk = 0; kk < 4; kk++) {
                int ty = ty0 + kk * 8;
                gW2T[(size_t)(c0 + ty) * 1024 + r0 + tx] = f2b(tile[tx][ty]);
            }
        }
    }
}

// ---- decoder: 2 independent chains (rows 0-31 / 32-63) + consumers: cooperative, 256 blocks ----
// bx 0..63: attention row b (chain b>>5); 64..127: GEMM (chain (bx-64)>>5, colslice (bx-64)&31);
// bx 128..255: logits consumers gated on both chains' gStep.
__global__ __launch_bounds__(256) void k_decoder(const float* __restrict__ h2o_b,
                                                 float* __restrict__ out) {
    __shared__ u16 sWh[64 * 512];
    __shared__ u16 sWx[64 * 512];
    __shared__ float s_z[4][32][17];
    __shared__ u16 s_hout[32 * 16];
    __shared__ float s_h[512];
    __shared__ float s_dt[512];
    __shared__ float s_av[512];
    __shared__ float s_att[64];
    __shared__ float s_red[256];
    __shared__ float s_mv[4][520];
    int tid = threadIdx.x, l = tid & 63, wid = tid >> 6;
    int bx = blockIdx.x;
    int ar = l & 15, ak = (l >> 4) * 8, rb = (l >> 4) * 4;
    int aoff = (l >> 4) * 16;
    if (bx >= 128) {
        // ======== consumers: 128 blocks ========
        u16* csA = sWh;
        u16* csB = sWh + 128 * 64;
        int wr = wid >> 1, wc = wid & 1;
        int srow = wid * 32 + (l >> 3);
        int scol = (l & 7) * 8;
        int ci = bx - 128;
        for (int jt = 0; jt < 63; jt++) {
            int T = ci + 128 * jt;
            if (T >= 8000) break;
            int byy = T / 250, bxx = T % 250;
            unsigned tgt = (unsigned)(2 * byy + 2);
            if (tid == 0) {
                while (ld1(&gStep) < tgt) __builtin_amdgcn_s_sleep(32);
                while (ld1(&gStep2) < tgt) __builtin_amdgcn_s_sleep(32);
            }
            __syncthreads();
            int rowM = byy * 128, colN = bxx * 128;
            f32x4 acc[4][4];
#pragma unroll
            for (int m = 0; m < 4; m++)
#pragma unroll
                for (int n = 0; n < 4; n++) acc[m][n] = (f32x4){0.f, 0.f, 0.f, 0.f};
            for (int k0 = 0; k0 < 1024; k0 += 64) {
#pragma unroll
                for (int c = 0; c < 4; c++) {
                    int r = srow + c * 8;
                    g2l16(gHcat + (size_t)(rowM + r) * 1024 + k0 + scol, csA + r * 64 + scol);
                    g2l16nt(gW2T + (size_t)(colN + r) * 1024 + k0 + scol, csB + r * 64 + scol);
                }
                __syncthreads();
#pragma unroll
                for (int ks = 0; ks < 2; ks++) {
                    bf16x8 a[4], b[4];
#pragma unroll
                    for (int m = 0; m < 4; m++) a[m] = *(const bf16x8*)(csA + (wr * 64 + m * 16 + ar) * 64 + ks * 32 + ak);
#pragma unroll
                    for (int n = 0; n < 4; n++) b[n] = *(const bf16x8*)(csB + (wc * 64 + n * 16 + ar) * 64 + ks * 32 + ak);
#pragma unroll
                    for (int m = 0; m < 4; m++)
#pragma unroll
                        for (int n = 0; n < 4; n++)
                            acc[m][n] = __builtin_amdgcn_mfma_f32_16x16x32_bf16(a[m], b[n], acc[m][n], 0, 0, 0);
                }
                __syncthreads();
            }
#pragma unroll
            for (int m = 0; m < 4; m++)
#pragma unroll
                for (int n = 0; n < 4; n++)
#pragma unroll
                    for (int ri = 0; ri < 4; ri++) {
                        int row = rowM + wr * 64 + m * 16 + rb + ri;
                        int col = colN + wc * 64 + n * 16 + ar;
                        out[(size_t)((row & 63) * 64 + (row >> 6)) * VT + col] = acc[m][n][ri] + h2o_b[col];
                    }
        }
        return;
    }
    if (bx >= 64) {
        // ======== GEMM: chain c, col-slice j ========
        int c = (bx - 64) >> 5, j = (bx - 64) & 31, cb = 32 * c;
        int mt = wid & 1, gp = wid >> 1;
#pragma unroll
        for (int it = 0; it < 16; it++) {
            int idx = it * 256 + tid;
            int lr = idx >> 6, kc = idx & 63;
            int gcol = (lr >> 4) * 512 + j * 16 + (lr & 15);
            int off = (lr * 1024 + kc * 16) ^ ((lr & 7) << 4);
            *(ushort8*)((char*)sWh + off) = *(const ushort8*)(gDecWhT + (size_t)gcol * 512 + kc * 8);
            *(ushort8*)((char*)sWx + off) = *(const ushort8*)(gDecWxTc + (size_t)gcol * 512 + kc * 8);
        }
        __syncthreads();
        int cell0 = tid, cell1 = tid + 256;
        int r30 = cell0 >> 4, hc0 = cell0 & 15;
        int r31 = cell1 >> 4, hc1 = cell1 & 15;
        int arow2 = cb + mt * 16 + ar;
        for (int t = 0; t < LL; t++) {
            // prefetch gate inputs for this step's 2 cells (no flag dependence)
            float xwv[2][4];
            const float* xw0 = gXWxD + (size_t)(t * 64 + cb + r30) * G4;
            const float* xw1 = gXWxD + (size_t)(t * 64 + cb + r31) * G4;
#pragma unroll
            for (int g = 0; g < 4; g++) {
                xwv[0][g] = xw0[g * 512 + 16 * j + hc0];
                xwv[1][g] = xw1[g * 512 + 16 * j + hc1];
            }
            // ---- phase A: zh (this chain's rows only) ----
            if (t > 0) waitflags(gFlagC + cb, 32, (unsigned)t);
            if (t > 0 && j == 0 && tid == 0)
                st32b(c ? (u32*)&gStep2 : (u32*)&gStep, (unsigned)t);
            bf16x8 af[16];
            const char* baseA = (t == 0)
                ? ((const char*)gEncHb + (size_t)(63 * 64 + arow2) * 1024 + aoff)
                : ((const char*)gHcat + (size_t)((t - 1) * 64 + arow2) * 2048 + aoff);
            ld16(baseA, af);
            f32x4 acc[2];
            acc[0] = (f32x4){0.f, 0.f, 0.f, 0.f};
            acc[1] = (f32x4){0.f, 0.f, 0.f, 0.f};
#pragma unroll
            for (int kk = 0; kk < 16; kk++) {
                int k = kk * 32 + ak;
#pragma unroll
                for (int gi = 0; gi < 2; gi++) {
                    int lr = (2 * gp + gi) * 16 + ar;
                    bf16x8 b = *(const bf16x8*)((char*)sWh + ((lr * 1024 + k * 2) ^ ((lr & 7) << 4)));
                    acc[gi] = __builtin_amdgcn_mfma_f32_16x16x32_bf16(af[kk], b, acc[gi], 0, 0, 0);
                }
            }
            // ---- phase C: + ctx (this chain's rows) @ WxC ----
            waitflags(gFlagB + cb, 32, (unsigned)(t + 1));
            bf16x8 cf[16];
            ld16((const char*)gHcat + (size_t)(t * 64 + arow2) * 2048 + 1024 + aoff, cf);
#pragma unroll
            for (int kk = 0; kk < 16; kk++) {
                int k = kk * 32 + ak;
#pragma unroll
                for (int gi = 0; gi < 2; gi++) {
                    int lr = (2 * gp + gi) * 16 + ar;
                    bf16x8 b = *(const bf16x8*)((char*)sWx + ((lr * 1024 + k * 2) ^ ((lr & 7) << 4)));
                    acc[gi] = __builtin_amdgcn_mfma_f32_16x16x32_bf16(cf[kk], b, acc[gi], 0, 0, 0);
                }
            }
            // exchange gates via LDS (gates split across waves)
#pragma unroll
            for (int gi = 0; gi < 2; gi++)
#pragma unroll
                for (int ri = 0; ri < 4; ri++)
                    s_z[2 * gp + gi][mt * 16 + rb + ri][ar] = acc[gi][ri];
            __syncthreads();
            // gates: 2 cells per thread
            {
                float zi = s_z[0][r30][hc0] + xwv[0][0];
                float zf = s_z[1][r30][hc0] + xwv[0][1];
                float zg = s_z[2][r30][hc0] + xwv[0][2];
                float zo = s_z[3][r30][hc0] + xwv[0][3];
                float co = gC[(cb + r30) * HH + 16 * j + hc0];
                float cn = sigm(zf) * co + sigm(zi) * ftanh(zg);
                float hn = sigm(zo) * ftanh(cn);
                gC[(cb + r30) * HH + 16 * j + hc0] = cn;
                s_hout[r30 * 16 + hc0] = f2b(hn);
                zi = s_z[0][r31][hc1] + xwv[1][0];
                zf = s_z[1][r31][hc1] + xwv[1][1];
                zg = s_z[2][r31][hc1] + xwv[1][2];
                zo = s_z[3][r31][hc1] + xwv[1][3];
                co = gC[(cb + r31) * HH + 16 * j + hc1];
                cn = sigm(zf) * co + sigm(zi) * ftanh(zg);
                hn = sigm(zo) * ftanh(cn);
                gC[(cb + r31) * HH + 16 * j + hc1] = cn;
                s_hout[r31 * 16 + hc1] = f2b(hn);
            }
            __syncthreads();
            if (tid < 128) {
                int row = tid >> 2, seg = tid & 3;
                u32x2 v = *(const u32x2*)(s_hout + row * 16 + seg * 4);
                st8b(gHcat + (size_t)(t * 64 + cb + row) * 1024 + j * 16 + seg * 4, v);
            }
            setflag(gFlagC + cb + j, (unsigned)(t + 1));
        }
        if (j == 0) {
            waitflags(gFlagC + cb, 32, 64u);
            waitflags(gFlagB + cb, 32, 64u);
            if (tid == 0) st32b(c ? (u32*)&gStep2 : (u32*)&gStep, 64u);
        }
        return;
    }
    // ======== attention row b (chain b>>5) ========
    {
        int b = bx;
        int cb = (b >> 5) << 5;
        s_av[tid] = gAv[tid];
        s_av[tid + 256] = gAv[tid + 256];
        __syncthreads();
        for (int t = 0; t < LL; t++) {
            if (t > 0) waitflags(gFlagC + cb, 32, (unsigned)t);
            const char* hb = (t == 0) ? ((const char*)gEncHb + (size_t)(63 * 64 + b) * 1024)
                                      : ((const char*)gHcat + (size_t)((t - 1) * 64 + b) * 2048);
            u32 hw = ld1(hb + 4 * tid);
            s_h[2 * tid] = b2f((u16)(hw & 0xffff));
            s_h[2 * tid + 1] = b2f((u16)(hw >> 16));
            __syncthreads();
            {
                int c8 = tid & 63, kq = tid >> 6;
                float a8[8];
#pragma unroll
                for (int jj = 0; jj < 8; jj++) a8[jj] = 0.f;
                const u8* wp = gWs8 + (size_t)(kq * 128) * 512 + c8 * 8;
#pragma unroll 4
                for (int i = 0; i < 128; i++) {
                    u32x2 w = *(const u32x2*)(wp + (size_t)i * 512);
                    float hk = s_h[kq * 128 + i];
                    a8[0] += hk * DEC8(w.x, 0);
                    a8[1] += hk * DEC8(w.x, 1);
                    a8[2] += hk * DEC8(w.x, 2);
                    a8[3] += hk * DEC8(w.x, 3);
                    a8[4] += hk * DEC8(w.y, 0);
                    a8[5] += hk * DEC8(w.y, 1);
                    a8[6] += hk * DEC8(w.y, 2);
                    a8[7] += hk * DEC8(w.y, 3);
                }
#pragma unroll
                for (int jj = 0; jj < 8; jj++) s_mv[kq][c8 * 8 + jj] = a8[jj];
            }
            __syncthreads();
            s_dt[tid] = s_mv[0][tid] + s_mv[1][tid] + s_mv[2][tid] + s_mv[3][tid];
            s_dt[tid + 256] = s_mv[0][tid + 256] + s_mv[1][tid + 256] + s_mv[2][tid + 256] + s_mv[3][tid + 256];
            __syncthreads();
            {
                int s = tid >> 2, q = tid & 3;
                const u16* et = gEncTb + (size_t)(b * 64 + s) * 512 + q * 128;
                const float* dtp = s_dt + q * 128;
                const float* avp = s_av + q * 128;
                float p = 0.f;
#pragma unroll
                for (int i = 0; i < 16; i++) {
                    ushort8 ev = *(const ushort8*)(et + i * 8);
#pragma unroll
                    for (int jj = 0; jj < 8; jj++) {
                        int h = i * 8 + jj;
                        p += ftanh(b2f((u16)ev[jj]) + dtp[h]) * avp[h];
                    }
                }
                s_red[tid] = p;
            }
            __syncthreads();
            if (tid < 64) {
                float v = s_red[tid * 4] + s_red[tid * 4 + 1] + s_red[tid * 4 + 2] + s_red[tid * 4 + 3];
                float m = v;
                for (int o = 32; o; o >>= 1) m = fmaxf(m, __shfl_xor(m, o));
                float e = __expf(v - m);
                float ss = e;
                for (int o = 32; o; o >>= 1) ss += __shfl_xor(ss, o);
                s_att[tid] = e / ss;
            }
            __syncthreads();
            int c = tid * 2;
            float c0 = 0.f, c1 = 0.f;
            const u16* eh = gEncHb2 + (size_t)b * LL * HH;
#pragma unroll 8
            for (int s2 = 0; s2 < 64; s2++) {
                float a = s_att[s2];
                u32 w = *(const u32*)(eh + (size_t)s2 * HH + c);
                c0 += a * b2f((u16)(w & 0xffff));
                c1 += a * b2f((u16)(w >> 16));
            }
            u32 cw = (u32)f2b(c0) | ((u32)f2b(c1) << 16);
            st32b((u32*)(gHcat + (size_t)(t * 64 + b) * 1024 + 512 + c), cw);
            setflag(gFlagB + b, (unsigned)(t + 1));
        }
    }
}

// ---------------- log-softmax in place, online max/sum, float4 ----------------
__global__ __launch_bounds__(256) void k_lsm(float* __restrict__ out) {
    int row = blockIdx.x, tid = threadIdx.x;
    float4* p4 = (float4*)(out + (size_t)row * VT);
    float m = -1e30f, s = 0.f;
    for (int i = tid; i < VT / 4; i += 256) {
        float4 v = p4[i];
        float mx = fmaxf(fmaxf(v.x, v.y), fmaxf(v.z, v.w));
        float mn = fmaxf(m, mx);
        s = s * __expf(m - mn) + __expf(v.x - mn) + __expf(v.y - mn) + __expf(v.z - mn) + __expf(v.w - mn);
        m = mn;
    }
    for (int o = 32; o; o >>= 1) {
        float m2 = __shfl_xor(m, o), s2 = __shfl_xor(s, o);
        float mn = fmaxf(m, m2);
        s = s * __expf(m - mn) + s2 * __expf(m2 - mn);
        m = mn;
    }
    __shared__ float rm[4], rs[4];
    if ((tid & 63) == 0) { rm[tid >> 6] = m; rs[tid >> 6] = s; }
    __syncthreads();
    float mm = fmaxf(fmaxf(rm[0], rm[1]), fmaxf(rm[2], rm[3]));
    float ss = rs[0] * __expf(rm[0] - mm) + rs[1] * __expf(rm[1] - mm) +
               rs[2] * __expf(rm[2] - mm) + rs[3] * __expf(rm[3] - mm);
    float lse = mm + __logf(ss);
    for (int i = tid; i < VT / 4; i += 256) {
        float4 v = p4[i];
        v.x -= lse; v.y -= lse; v.z -= lse; v.w -= lse;
        p4[i] = v;
    }
}

extern "C" void kernel_launch(void* const* d_in, const int* in_sizes, int n_in,
                              void* d_out, int out_size, void* d_ws, size_t ws_size,
                              hipStream_t stream) {
    const int*   src       = (const int*)d_in[0];
    const int*   tgt       = (const int*)d_in[1];
    const float* src_embed = (const float*)d_in[2];
    const float* enc_Wx    = (const float*)d_in[3];
    const float* enc_Wh    = (const float*)d_in[4];
    const float* enc_b     = (const float*)d_in[5];
    const float* tgt_embed = (const float*)d_in[6];
    const float* att_Wh    = (const float*)d_in[7];
    const float* att_Ws    = (const float*)d_in[8];
    const float* att_v     = (const float*)d_in[9];
    const float* dec_Wx    = (const float*)d_in[10];
    const float* dec_Wh    = (const float*)d_in[11];
    const float* dec_b     = (const float*)d_in[12];
    const float* h2o_W     = (const float*)d_in[13];
    const float* h2o_b     = (const float*)d_in[14];
    float* out = (float*)d_out;
    dim3 blk(256);

    k_transpose<<<dim3(G4 / 32, EE / 32), blk, 0, stream>>>(enc_Wx, EE, G4, 1);
    k_transpose<<<dim3(G4 / 32, HH / 32), blk, 0, stream>>>(enc_Wh, HH, G4, 2);
    k_transpose<<<dim3(HH / 32, HH / 32), blk, 0, stream>>>(att_Wh, HH, HH, 3);
    k_transpose<<<dim3(G4 / 32, EE / 32), blk, 0, stream>>>(dec_Wx, EE, G4, 4);
    k_transpose<<<dim3(G4 / 32, HH / 32), blk, 0, stream>>>(dec_Wx + (size_t)512 * G4, HH, G4, 5);
    k_transpose<<<dim3(G4 / 32, HH / 32), blk, 0, stream>>>(dec_Wh, HH, G4, 6);
    k_tofp8<<<HH * HH / 256, blk, 0, stream>>>(att_Ws);
    k_gather<<<RT, blk, 0, stream>>>(src, src_embed, 0);
    k_gather<<<RT, blk, 0, stream>>>(tgt, tgt_embed, 1);
    k_zero<<<128, blk, 0, stream>>>();
    // hoisted encoder-input GEMM (+bias folded)
    k_gemm<<<dim3(G4 / 128, RT / 128), blk, 0, stream>>>(0, 512, 0, 512, RT, G4, 512, 2, enc_b, 0);
    // encoder + co-launched XWxD GEMM + h2o_W transpose (cooperative, 256 blocks)
    const float* decb = dec_b;
    const float* h2ow = h2o_W;
    void* eargs[] = { (void*)&decb, (void*)&h2ow };
    hipLaunchCooperativeKernel((const void*)k_encoder, dim3(256), dim3(256), eargs, 0, stream);
    // enc_t = enc_hiddens @ att_Wh -> bf16, b-major [b*64+s][h]
    k_gemm<<<dim3(HH / 128, RT / 128), blk, 0, stream>>>(2, 512, 2, 512, RT, HH, 512, 4, nullptr, 2);
    k_rst<<<1, blk, 0, stream>>>(att_v);
    // 2-chain decoder + gStep-gated logits GEMM (cooperative, 256 blocks)
    const float* h2ob = h2o_b;
    float* outp = out;
    void* dargs[] = { (void*)&h2ob, (void*)&outp };
    hipLaunchCooperativeKernel((const void*)k_decoder, dim3(256), dim3(256), dargs, 0, stream);
    // in-place log-softmax
    k_lsm<<<RT, blk, 0, stream>>>(out);
}

// Round 17
// 2750.527 us; speedup vs baseline: 1.1050x; 1.1050x over previous
//
#include <hip/hip_runtime.h>
#include <hip/hip_bf16.h>
#include <math.h>

#define BB 64
#define LL 64
#define EE 512
#define HH 512
#define G4 2048
#define VT 32000
#define RT 4096  // LL*BB

typedef unsigned short u16;
typedef unsigned int u32;
typedef unsigned char u8;
typedef __attribute__((ext_vector_type(2))) unsigned int u32x2;
typedef __attribute__((ext_vector_type(8))) unsigned short ushort8;
typedef __attribute__((ext_vector_type(8))) short bf16x8;
typedef __attribute__((ext_vector_type(4))) float f32x4;

// ---------------- static device scratch ----------------
__device__ u16   gW2T[(size_t)VT * 1024];   // h2o_W^T (VT x 1024) bf16
__device__ u16   gEncWxT[G4 * EE];
__device__ u16   gEncWhT[G4 * HH];
__device__ u16   gAttWhT[HH * HH];
__device__ u16   gDecWxTe[G4 * EE];
__device__ u16   gDecWxTc[G4 * HH];
__device__ u16   gDecWhT[G4 * HH];
__device__ u8    gWs8[HH * HH];             // att_Ws fp8 e4m3, [k][c] layout
__device__ u16   gSrcEmb[RT * EE];
__device__ u16   gTgtEmb[RT * EE];
__device__ float gXWxE[(size_t)RT * G4];    // src_emb @ enc_Wx + enc_b
__device__ float gXWxD[(size_t)RT * G4];    // tgt_emb @ dec_Wx[:512] + dec_b
__device__ u16   gEncHb[(size_t)RT * HH];   // enc h bf16, [t*64+b][h]
__device__ u16   gEncHb2[(size_t)RT * HH];  // enc h bf16, [b*64+t][h]
__device__ u16   gEncTb[(size_t)RT * HH];   // enc_hiddens @ att_Wh, bf16 [b*64+s][h]
__device__ u16   gHcat[(size_t)RT * 1024];  // [h | ctx] bf16, row rr=t*64+b
__device__ float gC[BB * HH];               // LSTM cell state
__device__ float gAv[HH];
__device__ unsigned gFlagE[64];             // encoder: per-block h-ready generation
__device__ unsigned gFlagB[64];             // decoder: ctx ready (64 used)
__device__ unsigned gFlagC[64];             // decoder: h ready (32 used)
__device__ unsigned gStep;                  // aggregated "steps < gStep fully done"

__device__ __forceinline__ u16 f2b(float f) {
    union { float f; unsigned u; } v{f};
    unsigned r = v.u + 0x7fffu + ((v.u >> 16) & 1u);
    return (u16)(r >> 16);
}
__device__ __forceinline__ float b2f(u16 x) {
    union { unsigned u; float f; } v; v.u = ((unsigned)x) << 16; return v.f;
}
__device__ __forceinline__ float sigm(float x) { return 1.f / (1.f + __expf(-x)); }
__device__ __forceinline__ float ftanh(float x) {
    x = fminf(15.f, fmaxf(-15.f, x));
    float e = __expf(2.f * x);
    return (e - 1.f) / (e + 1.f);
}

// ---- fp8 e4m3 encode (preamble only) / decode (hot loop) ----
__device__ unsigned char encf8(float f) {
    union { float f; unsigned u; } v{f};
    unsigned s = (v.u >> 31) << 7;
    float af = fabsf(f);
    if (af < 0.0009765625f) return (unsigned char)s;
    if (af >= 448.f) return (unsigned char)(s | 0x7E);
    if (af < 0.015625f) {
        int q = (int)rintf(af * 512.f);
        if (q >= 8) return (unsigned char)(s | 0x08);
        return (unsigned char)(s | q);
    }
    int e; float m = frexpf(af, &e);
    int E = e - 1 + 7;
    int q = (int)rintf((m * 2.f - 1.f) * 8.f);
    if (q == 8) { E++; q = 0; }
    if (E >= 15) return (unsigned char)(s | 0x7E);
    return (unsigned char)(s | (E << 3) | q);
}
__device__ __forceinline__ float decf8s(unsigned v) {
    unsigned s = v >> 7, e = (v >> 3) & 15, m = v & 7;
    float mag = e ? ldexpf((float)(8 + m), (int)e - 10) : ldexpf((float)m, -9);
    return s ? -mag : mag;
}
#if __has_builtin(__builtin_amdgcn_cvt_f32_fp8)
#define DEC8(w, sel) __builtin_amdgcn_cvt_f32_fp8((int)(w), sel)
#else
#define DEC8(w, sel) decf8s(((w) >> (8 * (sel))) & 0xFFu)
#endif

// ---- L2-bypass (MALL-coherent) memory helpers ----
__device__ __forceinline__ void ld16(const void* addr, bf16x8* a) {
    asm volatile(
        "global_load_dwordx4 %0, %16, off sc0 sc1\n\t"
        "global_load_dwordx4 %1, %16, off offset:64 sc0 sc1\n\t"
        "global_load_dwordx4 %2, %16, off offset:128 sc0 sc1\n\t"
        "global_load_dwordx4 %3, %16, off offset:192 sc0 sc1\n\t"
        "global_load_dwordx4 %4, %16, off offset:256 sc0 sc1\n\t"
        "global_load_dwordx4 %5, %16, off offset:320 sc0 sc1\n\t"
        "global_load_dwordx4 %6, %16, off offset:384 sc0 sc1\n\t"
        "global_load_dwordx4 %7, %16, off offset:448 sc0 sc1\n\t"
        "global_load_dwordx4 %8, %16, off offset:512 sc0 sc1\n\t"
        "global_load_dwordx4 %9, %16, off offset:576 sc0 sc1\n\t"
        "global_load_dwordx4 %10, %16, off offset:640 sc0 sc1\n\t"
        "global_load_dwordx4 %11, %16, off offset:704 sc0 sc1\n\t"
        "global_load_dwordx4 %12, %16, off offset:768 sc0 sc1\n\t"
        "global_load_dwordx4 %13, %16, off offset:832 sc0 sc1\n\t"
        "global_load_dwordx4 %14, %16, off offset:896 sc0 sc1\n\t"
        "global_load_dwordx4 %15, %16, off offset:960 sc0 sc1\n\t"
        "s_waitcnt vmcnt(0)"
        : "=&v"(a[0]), "=&v"(a[1]), "=&v"(a[2]), "=&v"(a[3]),
          "=&v"(a[4]), "=&v"(a[5]), "=&v"(a[6]), "=&v"(a[7]),
          "=&v"(a[8]), "=&v"(a[9]), "=&v"(a[10]), "=&v"(a[11]),
          "=&v"(a[12]), "=&v"(a[13]), "=&v"(a[14]), "=&v"(a[15])
        : "v"(addr) : "memory");
}
__device__ __forceinline__ u32 ld1(const void* addr) {
    u32 r;
    asm volatile("global_load_dword %0, %1, off sc0 sc1\n\ts_waitcnt vmcnt(0)"
                 : "=&v"(r) : "v"(addr) : "memory");
    return r;
}
__device__ __forceinline__ void st8b(void* p, u32x2 v) {
    asm volatile("global_store_dwordx2 %0, %1, off sc0 sc1" :: "v"(p), "v"(v) : "memory");
}
__device__ __forceinline__ void st32b(u32* p, u32 v) {
    asm volatile("global_store_dword %0, %1, off sc0 sc1" :: "v"(p), "v"(v) : "memory");
}

__device__ __forceinline__ void setflag(unsigned* f, unsigned v) {
    asm volatile("s_waitcnt vmcnt(0)" ::: "memory");
    __syncthreads();
    if (threadIdx.x == 0) st32b((u32*)f, v);
}
__device__ __forceinline__ void waitflags(unsigned* flags, int n, unsigned target) {
    if (threadIdx.x < 64) {
        const unsigned* p = flags + (threadIdx.x & (n - 1));
        for (;;) {
            u32 v = ld1(p);
            if (__all(v >= target)) break;
            __builtin_amdgcn_s_sleep(1);
        }
    }
    __syncthreads();
}

__device__ __forceinline__ void g2l16(const u16* g, u16* l) {
    __builtin_amdgcn_global_load_lds(
        (const __attribute__((address_space(1))) unsigned int*)g,
        (__attribute__((address_space(3))) unsigned int*)l, 16, 0, 0);
}
__device__ __forceinline__ void g2l16nt(const u16* g, u16* l) {
    __builtin_amdgcn_global_load_lds(
        (const __attribute__((address_space(1))) unsigned int*)g,
        (__attribute__((address_space(3))) unsigned int*)l, 16, 0, 2);
}

// ---- fused preamble: transposes + fp8 encode + gathers + state init ----
// grid 1936: [0,1344) transposes (4 tiles each); [1344,1408) Ws fp8;
// [1408,1664) src gather; [1664,1920) tgt gather; [1920,1936) gC zero + flags/av.
__global__ __launch_bounds__(256) void k_prep(
    const int* __restrict__ src, const int* __restrict__ tgt,
    const float* __restrict__ src_embed, const float* __restrict__ tgt_embed,
    const float* __restrict__ enc_Wx, const float* __restrict__ enc_Wh,
    const float* __restrict__ att_Wh, const float* __restrict__ dec_Wx,
    const float* __restrict__ dec_Wh, const float* __restrict__ att_Ws,
    const float* __restrict__ av) {
    int bx = blockIdx.x, tid = threadIdx.x;
    if (bx < 1344) {
        __shared__ float tile[32][33];
        int tx = tid & 31, ty0 = tid >> 5;
#pragma unroll 1
        for (int q = 0; q < 4; q++) {
            int ti = bx * 4 + q;  // 0..5375
            const float* in; u16* outp; int C, rel;
            if (ti < 1024)      { in = enc_Wx;  outp = gEncWxT;  C = 2048; rel = ti; }
            else if (ti < 2048) { in = enc_Wh;  outp = gEncWhT;  C = 2048; rel = ti - 1024; }
            else if (ti < 2304) { in = att_Wh;  outp = gAttWhT;  C = 512;  rel = ti - 2048; }
            else if (ti < 3328) { in = dec_Wx;  outp = gDecWxTe; C = 2048; rel = ti - 2304; }
            else if (ti < 4352) { in = dec_Wx + (size_t)512 * 2048; outp = gDecWxTc; C = 2048; rel = ti - 3328; }
            else                { in = dec_Wh;  outp = gDecWhT;  C = 2048; rel = ti - 4352; }
            int tpr = C / 32;
            int c0 = (rel % tpr) * 32, r0 = (rel / tpr) * 32;
            __syncthreads();
#pragma unroll
            for (int k = 0; k < 4; k++) {
                int ty = ty0 + k * 8;
                tile[ty][tx] = in[(size_t)(r0 + ty) * C + c0 + tx];
            }
            __syncthreads();
#pragma unroll
            for (int k = 0; k < 4; k++) {
                int ty = ty0 + k * 8;
                outp[(size_t)(c0 + ty) * 512 + r0 + tx] = f2b(tile[tx][ty]);
            }
        }
    } else if (bx < 1408) {
        int base = (bx - 1344) * 4096;
        for (int i = tid; i < 4096; i += 256) gWs8[base + i] = encf8(att_Ws[base + i]);
    } else if (bx < 1664) {
        int r0 = (bx - 1408) * 16;
        for (int rr = 0; rr < 16; rr++) {
            int r = r0 + rr, b = r & 63, t = r >> 6;
            int token = src[b * LL + t];
            const float* srow = src_embed + (size_t)token * EE;
            for (int e = tid; e < EE; e += 256)
                gSrcEmb[(size_t)r * EE + e] = f2b(srow[e]);
        }
    } else if (bx < 1920) {
        int r0 = (bx - 1664) * 16;
        for (int rr = 0; rr < 16; rr++) {
            int r = r0 + rr, b = r & 63, t = r >> 6;
            int token = tgt[b * LL + t];
            const float* srow = tgt_embed + (size_t)token * EE;
            for (int e = tid; e < EE; e += 256)
                gTgtEmb[(size_t)r * EE + e] = f2b(srow[e]);
        }
    } else {
        int base = (bx - 1920) * 2048;
        for (int i = tid; i < 2048; i += 256) gC[base + i] = 0.f;
        if (bx == 1920) {
            if (tid < 64) {
                st32b((u32*)(gFlagE + tid), 0u);
                st32b((u32*)(gFlagB + tid), 0u);
                st32b((u32*)(gFlagC + tid), 0u);
            }
            if (tid == 0) st32b((u32*)&gStep, 0u);
            gAv[tid] = av[tid];
            gAv[tid + 256] = av[tid + 256];
        }
    }
}

// ---------------- generic bf16 MFMA GEMM (preamble): epi2 fp32+bias, epi4 bf16 b-major ----------------
__global__ __launch_bounds__(256) void k_gemm(int selA, int lda, int selB, int ldb,
                                              int M, int N, int K, int epi,
                                              const float* __restrict__ bias, int selOut) {
    __shared__ u16 sA[128 * 72];
    __shared__ u16 sB[128 * 72];
    const u16* Ag = (selA == 0) ? gSrcEmb : gEncHb;
    const u16* Bg = (selB == 0) ? gEncWxT : gAttWhT;
    float* Cg = gXWxE;

    int tid = threadIdx.x, l = tid & 63, wid = tid >> 6, wr = wid >> 1, wc = wid & 1;
    int ar = l & 15, ak = (l >> 4) * 8;
    int rowM = blockIdx.y * 128, colN = blockIdx.x * 128;
    f32x4 acc[4][4];
#pragma unroll
    for (int m = 0; m < 4; m++)
#pragma unroll
        for (int n = 0; n < 4; n++) acc[m][n] = (f32x4){0.f, 0.f, 0.f, 0.f};

    for (int k0 = 0; k0 < K; k0 += 64) {
#pragma unroll
        for (int it = 0; it < 4; it++) {
            int idx = it * 256 + tid;
            int row = idx >> 3, cc = idx & 7;
            *(ushort8*)(sA + row * 72 + cc * 8) =
                *(const ushort8*)(Ag + (size_t)(rowM + row) * lda + k0 + cc * 8);
            *(ushort8*)(sB + row * 72 + cc * 8) =
                *(const ushort8*)(Bg + (size_t)(colN + row) * ldb + k0 + cc * 8);
        }
        __syncthreads();
#pragma unroll
        for (int ks = 0; ks < 2; ks++) {
            bf16x8 a[4], b[4];
#pragma unroll
            for (int m = 0; m < 4; m++) a[m] = *(const bf16x8*)(sA + (wr * 64 + m * 16 + ar) * 72 + ks * 32 + ak);
#pragma unroll
            for (int n = 0; n < 4; n++) b[n] = *(const bf16x8*)(sB + (wc * 64 + n * 16 + ar) * 72 + ks * 32 + ak);
#pragma unroll
            for (int m = 0; m < 4; m++)
#pragma unroll
                for (int n = 0; n < 4; n++)
                    acc[m][n] = __builtin_amdgcn_mfma_f32_16x16x32_bf16(a[m], b[n], acc[m][n], 0, 0, 0);
        }
        __syncthreads();
    }
    int rb = (l >> 4) * 4;
#pragma unroll
    for (int m = 0; m < 4; m++)
#pragma unroll
        for (int n = 0; n < 4; n++)
#pragma unroll
            for (int ri = 0; ri < 4; ri++) {
                int row = rowM + wr * 64 + m * 16 + rb + ri;
                int col = colN + wc * 64 + n * 16 + ar;
                float v = acc[m][n][ri];
                if (epi == 2) Cg[(size_t)row * N + col] = v + bias[col];
                else gEncTb[(size_t)((row & 63) * 64 + (row >> 6)) * N + col] = f2b(v);
            }
}

// ---- encoder + co-launched helpers: cooperative, 256 blocks (R15-proven) ----
__global__ __launch_bounds__(256) void k_encoder(const float* __restrict__ dec_b,
                                                 const float* __restrict__ h2o_W) {
    __shared__ char smem[67584];
    int tid = threadIdx.x, l = tid & 63, wid = tid >> 6;
    int bx = blockIdx.x;
    int ar = l & 15, ak = (l >> 4) * 8, rb = (l >> 4) * 4;
    if (bx < 32) {
        u16* sW = (u16*)smem;
        u16* s_hout = (u16*)(smem + 65536);
        int j = bx;
#pragma unroll
        for (int it = 0; it < 16; it++) {
            int idx = it * 256 + tid;
            int lr = idx >> 6, kc = idx & 63;
            int gcol = (lr >> 4) * 512 + j * 16 + (lr & 15);
            int off = (lr * 1024 + kc * 16) ^ ((lr & 7) << 4);
            *(ushort8*)((char*)sW + off) = *(const ushort8*)(gEncWhT + (size_t)gcol * 512 + kc * 8);
        }
        __syncthreads();
        int arow = wid * 16 + ar, aoff = (l >> 4) * 16;
        int hcol = j * 16 + ar;
        for (int t = 0; t < LL; t++) {
            float xwv[4][4];
#pragma unroll
            for (int ri = 0; ri < 4; ri++) {
                const float* xw = gXWxE + (size_t)(t * BB + wid * 16 + rb + ri) * G4;
#pragma unroll
                for (int g = 0; g < 4; g++) xwv[ri][g] = xw[g * 512 + hcol];
            }
            f32x4 acc[4];
#pragma unroll
            for (int g = 0; g < 4; g++) acc[g] = (f32x4){0.f, 0.f, 0.f, 0.f};
            if (t > 0) {
                waitflags(gFlagE, 32, (unsigned)t);
                bf16x8 af[16];
                ld16((const char*)gEncHb + (size_t)((t - 1) * BB + arow) * 1024 + aoff, af);
#pragma unroll
                for (int kk = 0; kk < 16; kk++) {
                    int k = kk * 32 + ak;
#pragma unroll
                    for (int g = 0; g < 4; g++) {
                        int lr = g * 16 + ar;
                        bf16x8 b = *(const bf16x8*)((char*)sW + ((lr * 1024 + k * 2) ^ ((lr & 7) << 4)));
                        acc[g] = __builtin_amdgcn_mfma_f32_16x16x32_bf16(af[kk], b, acc[g], 0, 0, 0);
                    }
                }
            }
#pragma unroll
            for (int ri = 0; ri < 4; ri++) {
                int row = wid * 16 + rb + ri;
                float zi = acc[0][ri] + xwv[ri][0];
                float zf = acc[1][ri] + xwv[ri][1];
                float zg = acc[2][ri] + xwv[ri][2];
                float zo = acc[3][ri] + xwv[ri][3];
                float co = gC[row * HH + hcol];
                float cn = sigm(zf) * co + sigm(zi) * ftanh(zg);
                float hn = sigm(zo) * ftanh(cn);
                gC[row * HH + hcol] = cn;
                s_hout[row * 16 + ar] = f2b(hn);
            }
            __syncthreads();
            {
                int row = tid >> 2, seg = tid & 3;
                u32x2 v = *(const u32x2*)(s_hout + row * 16 + seg * 4);
                st8b(gEncHb + (size_t)(t * BB + row) * HH + j * 16 + seg * 4, v);
                *(u32x2*)(gEncHb2 + (size_t)(row * LL + t) * HH + j * 16 + seg * 4) = v;
            }
            setflag(gFlagE + j, (unsigned)(t + 1));
        }
    } else if (bx < 96) {
        u16* sA = (u16*)smem;
        u16* sB = (u16*)(smem + 18432);
        int wr = wid >> 1, wc = wid & 1;
        for (int it8 = 0; it8 < 8; it8++) {
            int ti = (bx - 32) * 8 + it8;
            int bxx = ti & 15, byy = ti >> 4;
            int rowM = byy * 128, colN = bxx * 128;
            f32x4 acc[4][4];
#pragma unroll
            for (int m = 0; m < 4; m++)
#pragma unroll
                for (int n = 0; n < 4; n++) acc[m][n] = (f32x4){0.f, 0.f, 0.f, 0.f};
            for (int k0 = 0; k0 < 512; k0 += 64) {
#pragma unroll
                for (int it = 0; it < 4; it++) {
                    int idx = it * 256 + tid;
                    int row = idx >> 3, cc = idx & 7;
                    *(ushort8*)(sA + row * 72 + cc * 8) =
                        *(const ushort8*)(gTgtEmb + (size_t)(rowM + row) * 512 + k0 + cc * 8);
                    *(ushort8*)(sB + row * 72 + cc * 8) =
                        *(const ushort8*)(gDecWxTe + (size_t)(colN + row) * 512 + k0 + cc * 8);
                }
                __syncthreads();
#pragma unroll
                for (int ks = 0; ks < 2; ks++) {
                    bf16x8 a[4], b[4];
#pragma unroll
                    for (int m = 0; m < 4; m++) a[m] = *(const bf16x8*)(sA + (wr * 64 + m * 16 + ar) * 72 + ks * 32 + ak);
#pragma unroll
                    for (int n = 0; n < 4; n++) b[n] = *(const bf16x8*)(sB + (wc * 64 + n * 16 + ar) * 72 + ks * 32 + ak);
#pragma unroll
                    for (int m = 0; m < 4; m++)
#pragma unroll
                        for (int n = 0; n < 4; n++)
                            acc[m][n] = __builtin_amdgcn_mfma_f32_16x16x32_bf16(a[m], b[n], acc[m][n], 0, 0, 0);
                }
                __syncthreads();
            }
#pragma unroll
            for (int m = 0; m < 4; m++)
#pragma unroll
                for (int n = 0; n < 4; n++)
#pragma unroll
                    for (int ri = 0; ri < 4; ri++) {
                        int row = rowM + wr * 64 + m * 16 + rb + ri;
                        int col = colN + wc * 64 + n * 16 + ar;
                        gXWxD[(size_t)row * G4 + col] = acc[m][n][ri] + dec_b[col];
                    }
        }
    } else {
        float (*tile)[33] = (float(*)[33])smem;
        int tx = tid & 31, ty0 = tid >> 5;
        for (int k = 0; k < 200; k++) {
            int ti = (bx - 96) * 200 + k;
            int ct = ti % 1000, rt = ti / 1000;
            int c0 = ct * 32, r0 = rt * 32;
            __syncthreads();
#pragma unroll
            for (int kk = 0; kk < 4; kk++) {
                int ty = ty0 + kk * 8;
                tile[ty][tx] = h2o_W[(size_t)(r0 + ty) * VT + c0 + tx];
            }
            __syncthreads();
#pragma unroll
            for (int kk = 0; kk < 4; kk++) {
                int ty = ty0 + kk * 8;
                gW2T[(size_t)(c0 + ty) * 1024 + r0 + tx] = f2b(tile[tx][ty]);
            }
        }
    }
}

// ---- merged decoder + logits-GEMM consumers (R15-proven): cooperative, 256 blocks ----
__global__ __launch_bounds__(256) void k_decoder(const float* __restrict__ h2o_b,
                                                 float* __restrict__ out) {
    __shared__ u16 sWh[64 * 512];
    __shared__ u16 sWx[64 * 512];
    __shared__ u16 s_hout[64 * 16];
    __shared__ float s_h[512];
    __shared__ float s_dt[512];
    __shared__ float s_av[512];
    __shared__ float s_att[64];
    __shared__ float s_red[256];
    __shared__ float s_mv[4][520];
    int tid = threadIdx.x, l = tid & 63, wid = tid >> 6;
    int bx = blockIdx.x;
    int ar = l & 15, ak = (l >> 4) * 8, rb = (l >> 4) * 4;
    int arow = wid * 16 + ar, aoff = (l >> 4) * 16;
    if (bx >= 96) {
        // ======== consumer: gStep-gated logits GEMM tiles (cheap 1-lane poll) ========
        u16* csA = sWh;
        u16* csB = sWh + 128 * 64;
        int wr = wid >> 1, wc = wid & 1;
        int srow = wid * 32 + (l >> 3);
        int scol = (l & 7) * 8;
        int ci = bx - 96;
        for (int jt = 0; jt < 50; jt++) {
            int T = ci + 160 * jt;
            int byy = T / 250, bxx = T % 250;
            unsigned tgt = (unsigned)(2 * byy + 2);
            if (tid == 0) {
                while (ld1(&gStep) < tgt) __builtin_amdgcn_s_sleep(32);
            }
            __syncthreads();
            int rowM = byy * 128, colN = bxx * 128;
            f32x4 acc[4][4];
#pragma unroll
            for (int m = 0; m < 4; m++)
#pragma unroll
                for (int n = 0; n < 4; n++) acc[m][n] = (f32x4){0.f, 0.f, 0.f, 0.f};
            for (int k0 = 0; k0 < 1024; k0 += 64) {
#pragma unroll
                for (int c = 0; c < 4; c++) {
                    int r = srow + c * 8;
                    g2l16(gHcat + (size_t)(rowM + r) * 1024 + k0 + scol, csA + r * 64 + scol);
                    g2l16nt(gW2T + (size_t)(colN + r) * 1024 + k0 + scol, csB + r * 64 + scol);
                }
                __syncthreads();
#pragma unroll
                for (int ks = 0; ks < 2; ks++) {
                    bf16x8 a[4], b[4];
#pragma unroll
                    for (int m = 0; m < 4; m++) a[m] = *(const bf16x8*)(csA + (wr * 64 + m * 16 + ar) * 64 + ks * 32 + ak);
#pragma unroll
                    for (int n = 0; n < 4; n++) b[n] = *(const bf16x8*)(csB + (wc * 64 + n * 16 + ar) * 64 + ks * 32 + ak);
#pragma unroll
                    for (int m = 0; m < 4; m++)
#pragma unroll
                        for (int n = 0; n < 4; n++)
                            acc[m][n] = __builtin_amdgcn_mfma_f32_16x16x32_bf16(a[m], b[n], acc[m][n], 0, 0, 0);
                }
                __syncthreads();
            }
#pragma unroll
            for (int m = 0; m < 4; m++)
#pragma unroll
                for (int n = 0; n < 4; n++)
#pragma unroll
                    for (int ri = 0; ri < 4; ri++) {
                        int row = rowM + wr * 64 + m * 16 + rb + ri;
                        int col = colN + wc * 64 + n * 16 + ar;
                        out[(size_t)((row & 63) * 64 + (row >> 6)) * VT + col] = acc[m][n][ri] + h2o_b[col];
                    }
        }
        return;
    }
    // ======== producer side ========
    if (bx >= 64) {
        int j = bx - 64;
#pragma unroll
        for (int it = 0; it < 16; it++) {
            int idx = it * 256 + tid;
            int lr = idx >> 6, kc = idx & 63;
            int gcol = (lr >> 4) * 512 + j * 16 + (lr & 15);
            int off = (lr * 1024 + kc * 16) ^ ((lr & 7) << 4);
            *(ushort8*)((char*)sWh + off) = *(const ushort8*)(gDecWhT + (size_t)gcol * 512 + kc * 8);
            *(ushort8*)((char*)sWx + off) = *(const ushort8*)(gDecWxTc + (size_t)gcol * 512 + kc * 8);
        }
    } else {
        s_av[tid] = gAv[tid];
        s_av[tid + 256] = gAv[tid + 256];
    }
    __syncthreads();
    for (int t = 0; t < LL; t++) {
        if (bx >= 64) {
            int j = bx - 64;
            int hcol = j * 16 + ar;
            float xwv[4][4];
#pragma unroll
            for (int ri = 0; ri < 4; ri++) {
                const float* xw = gXWxD + (size_t)(t * BB + wid * 16 + rb + ri) * G4;
#pragma unroll
                for (int g = 0; g < 4; g++) xwv[ri][g] = xw[g * 512 + hcol];
            }
            // ---- phase A: zh = h_prev @ Wh_slice ----
            if (t > 0) waitflags(gFlagC, 32, (unsigned)t);
            if (t > 0 && bx == 64 && tid == 0) st32b((u32*)&gStep, (unsigned)t);
            bf16x8 af[16];
            const char* baseA = (t == 0)
                ? ((const char*)gEncHb + (size_t)(63 * BB + arow) * 1024 + aoff)
                : ((const char*)gHcat + (size_t)((t - 1) * BB + arow) * 2048 + aoff);
            ld16(baseA, af);
            f32x4 acc[4];
#pragma unroll
            for (int g = 0; g < 4; g++) acc[g] = (f32x4){0.f, 0.f, 0.f, 0.f};
#pragma unroll
            for (int kk = 0; kk < 16; kk++) {
                int k = kk * 32 + ak;
#pragma unroll
                for (int g = 0; g < 4; g++) {
                    int lr = g * 16 + ar;
                    bf16x8 b = *(const bf16x8*)((char*)sWh + ((lr * 1024 + k * 2) ^ ((lr & 7) << 4)));
                    acc[g] = __builtin_amdgcn_mfma_f32_16x16x32_bf16(af[kk], b, acc[g], 0, 0, 0);
                }
            }
            // ---- phase C: + ctx @ WxC -> gates -> h ----
            waitflags(gFlagB, 64, (unsigned)(t + 1));
            bf16x8 cf[16];
            ld16((const char*)gHcat + (size_t)(t * BB + arow) * 2048 + 1024 + aoff, cf);
#pragma unroll
            for (int kk = 0; kk < 16; kk++) {
                int k = kk * 32 + ak;
#pragma unroll
                for (int g = 0; g < 4; g++) {
                    int lr = g * 16 + ar;
                    bf16x8 b = *(const bf16x8*)((char*)sWx + ((lr * 1024 + k * 2) ^ ((lr & 7) << 4)));
                    acc[g] = __builtin_amdgcn_mfma_f32_16x16x32_bf16(cf[kk], b, acc[g], 0, 0, 0);
                }
            }
#pragma unroll
            for (int ri = 0; ri < 4; ri++) {
                int row = wid * 16 + rb + ri;
                float zi = acc[0][ri] + xwv[ri][0];
                float zf = acc[1][ri] + xwv[ri][1];
                float zg = acc[2][ri] + xwv[ri][2];
                float zo = acc[3][ri] + xwv[ri][3];
                float co = gC[row * HH + hcol];
                float cn = sigm(zf) * co + sigm(zi) * ftanh(zg);
                float hn = sigm(zo) * ftanh(cn);
                gC[row * HH + hcol] = cn;
                s_hout[row * 16 + ar] = f2b(hn);
            }
            __syncthreads();
            {
                int row = tid >> 2, seg = tid & 3;
                u32x2 v = *(const u32x2*)(s_hout + row * 16 + seg * 4);
                st8b(gHcat + (size_t)(t * BB + row) * 1024 + j * 16 + seg * 4, v);
            }
            setflag(gFlagC + j, (unsigned)(t + 1));
        } else {
            // ---- attention for batch row b ----
            int b = bx;
            if (t > 0) waitflags(gFlagC, 32, (unsigned)t);
            const char* hb = (t == 0) ? ((const char*)gEncHb + (size_t)(63 * BB + b) * 1024)
                                      : ((const char*)gHcat + (size_t)((t - 1) * BB + b) * 2048);
            u32 hw = ld1(hb + 4 * tid);
            s_h[2 * tid] = b2f((u16)(hw & 0xffff));
            s_h[2 * tid + 1] = b2f((u16)(hw >> 16));
            __syncthreads();
            {
                int c8 = tid & 63, kq = tid >> 6;
                float a8[8];
#pragma unroll
                for (int jj = 0; jj < 8; jj++) a8[jj] = 0.f;
                const u8* wp = gWs8 + (size_t)(kq * 128) * 512 + c8 * 8;
#pragma unroll 4
                for (int i = 0; i < 128; i++) {
                    u32x2 w = *(const u32x2*)(wp + (size_t)i * 512);
                    float hk = s_h[kq * 128 + i];
                    a8[0] += hk * DEC8(w.x, 0);
                    a8[1] += hk * DEC8(w.x, 1);
                    a8[2] += hk * DEC8(w.x, 2);
                    a8[3] += hk * DEC8(w.x, 3);
                    a8[4] += hk * DEC8(w.y, 0);
                    a8[5] += hk * DEC8(w.y, 1);
                    a8[6] += hk * DEC8(w.y, 2);
                    a8[7] += hk * DEC8(w.y, 3);
                }
#pragma unroll
                for (int jj = 0; jj < 8; jj++) s_mv[kq][c8 * 8 + jj] = a8[jj];
            }
            __syncthreads();
            s_dt[tid] = s_mv[0][tid] + s_mv[1][tid] + s_mv[2][tid] + s_mv[3][tid];
            s_dt[tid + 256] = s_mv[0][tid + 256] + s_mv[1][tid + 256] + s_mv[2][tid + 256] + s_mv[3][tid + 256];
            __syncthreads();
            {
                int s = tid >> 2, q = tid & 3;
                const u16* et = gEncTb + (size_t)(b * 64 + s) * 512 + q * 128;
                const float* dtp = s_dt + q * 128;
                const float* avp = s_av + q * 128;
                float p = 0.f;
#pragma unroll
                for (int i = 0; i < 16; i++) {
                    ushort8 ev = *(const ushort8*)(et + i * 8);
#pragma unroll
                    for (int jj = 0; jj < 8; jj++) {
                        int h = i * 8 + jj;
                        p += ftanh(b2f((u16)ev[jj]) + dtp[h]) * avp[h];
                    }
                }
                s_red[tid] = p;
            }
            __syncthreads();
            if (tid < 64) {
                float v = s_red[tid * 4] + s_red[tid * 4 + 1] + s_red[tid * 4 + 2] + s_red[tid * 4 + 3];
                float m = v;
                for (int o = 32; o; o >>= 1) m = fmaxf(m, __shfl_xor(m, o));
                float e = __expf(v - m);
                float ss = e;
                for (int o = 32; o; o >>= 1) ss += __shfl_xor(ss, o);
                s_att[tid] = e / ss;
            }
            __syncthreads();
            int c = tid * 2;
            float c0 = 0.f, c1 = 0.f;
            const u16* eh = gEncHb2 + (size_t)b * LL * HH;
#pragma unroll 8
            for (int s2 = 0; s2 < 64; s2++) {
                float a = s_att[s2];
                u32 w = *(const u32*)(eh + (size_t)s2 * HH + c);
                c0 += a * b2f((u16)(w & 0xffff));
                c1 += a * b2f((u16)(w >> 16));
            }
            u32 cw = (u32)f2b(c0) | ((u32)f2b(c1) << 16);
            st32b((u32*)(gHcat + (size_t)(t * BB + b) * 1024 + 512 + c), cw);
            setflag(gFlagB + b, (unsigned)(t + 1));
        }
    }
    if (bx == 64) {
        waitflags(gFlagC, 32, 64u);
        waitflags(gFlagB, 64, 64u);
        if (tid == 0) st32b((u32*)&gStep, 64u);
    }
}

// ---------------- log-softmax in place, online max/sum, float4 ----------------
__global__ __launch_bounds__(256) void k_lsm(float* __restrict__ out) {
    int row = blockIdx.x, tid = threadIdx.x;
    float4* p4 = (float4*)(out + (size_t)row * VT);
    float m = -1e30f, s = 0.f;
    for (int i = tid; i < VT / 4; i += 256) {
        float4 v = p4[i];
        float mx = fmaxf(fmaxf(v.x, v.y), fmaxf(v.z, v.w));
        float mn = fmaxf(m, mx);
        s = s * __expf(m - mn) + __expf(v.x - mn) + __expf(v.y - mn) + __expf(v.z - mn) + __expf(v.w - mn);
        m = mn;
    }
    for (int o = 32; o; o >>= 1) {
        float m2 = __shfl_xor(m, o), s2 = __shfl_xor(s, o);
        float mn = fmaxf(m, m2);
        s = s * __expf(m - mn) + s2 * __expf(m2 - mn);
        m = mn;
    }
    __shared__ float rm[4], rs[4];
    if ((tid & 63) == 0) { rm[tid >> 6] = m; rs[tid >> 6] = s; }
    __syncthreads();
    float mm = fmaxf(fmaxf(rm[0], rm[1]), fmaxf(rm[2], rm[3]));
    float ss = rs[0] * __expf(rm[0] - mm) + rs[1] * __expf(rm[1] - mm) +
               rs[2] * __expf(rm[2] - mm) + rs[3] * __expf(rm[3] - mm);
    float lse = mm + __logf(ss);
    for (int i = tid; i < VT / 4; i += 256) {
        float4 v = p4[i];
        v.x -= lse; v.y -= lse; v.z -= lse; v.w -= lse;
        p4[i] = v;
    }
}

extern "C" void kernel_launch(void* const* d_in, const int* in_sizes, int n_in,
                              void* d_out, int out_size, void* d_ws, size_t ws_size,
                              hipStream_t stream) {
    const int*   src       = (const int*)d_in[0];
    const int*   tgt       = (const int*)d_in[1];
    const float* src_embed = (const float*)d_in[2];
    const float* enc_Wx    = (const float*)d_in[3];
    const float* enc_Wh    = (const float*)d_in[4];
    const float* enc_b     = (const float*)d_in[5];
    const float* tgt_embed = (const float*)d_in[6];
    const float* att_Wh    = (const float*)d_in[7];
    const float* att_Ws    = (const float*)d_in[8];
    const float* att_v     = (const float*)d_in[9];
    const float* dec_Wx    = (const float*)d_in[10];
    const float* dec_Wh    = (const float*)d_in[11];
    const float* dec_b     = (const float*)d_in[12];
    const float* h2o_W     = (const float*)d_in[13];
    const float* h2o_b     = (const float*)d_in[14];
    float* out = (float*)d_out;
    dim3 blk(256);

    // fused preamble: transposes + fp8 + gathers + state init
    k_prep<<<1936, blk, 0, stream>>>(src, tgt, src_embed, tgt_embed,
                                     enc_Wx, enc_Wh, att_Wh, dec_Wx, dec_Wh,
                                     att_Ws, att_v);
    // hoisted encoder-input GEMM (+bias folded)
    k_gemm<<<dim3(G4 / 128, RT / 128), blk, 0, stream>>>(0, 512, 0, 512, RT, G4, 512, 2, enc_b, 0);
    // encoder + co-launched XWxD GEMM + h2o_W transpose (cooperative, 256 blocks)
    const float* decb = dec_b;
    const float* h2ow = h2o_W;
    void* eargs[] = { (void*)&decb, (void*)&h2ow };
    hipLaunchCooperativeKernel((const void*)k_encoder, dim3(256), dim3(256), eargs, 0, stream);
    // enc_t = enc_hiddens @ att_Wh -> bf16, b-major [b*64+s][h]
    k_gemm<<<dim3(HH / 128, RT / 128), blk, 0, stream>>>(2, 512, 2, 512, RT, HH, 512, 4, nullptr, 2);
    // merged decoder + gStep-gated logits GEMM (cooperative, 256 blocks)
    const float* h2ob = h2o_b;
    float* outp = out;
    void* dargs[] = { (void*)&h2ob, (void*)&outp };
    hipLaunchCooperativeKernel((const void*)k_decoder, dim3(256), dim3(256), dargs, 0, stream);
    // in-place log-softmax
    k_lsm<<<RT, blk, 0, stream>>>(out);
}